// Round 6
// baseline (320.760 us; speedup 1.0000x reference)
//
#include <hip/hip_runtime.h>
#include <hip/hip_bf16.h>

#define B_  2
#define S_  2048
#define D_  1024
#define H_  16
#define HD_ 64

typedef __attribute__((ext_vector_type(8))) short bf16x8;
typedef __attribute__((ext_vector_type(4))) float f32x4;

typedef __attribute__((address_space(1))) const short gbl_short;
typedef __attribute__((address_space(3))) short lds_short;

__device__ __forceinline__ short f2bf(float f) {
  union { float f; unsigned u; } v; v.f = f;
  unsigned r = (v.u + 0x7FFFu + ((v.u >> 16) & 1u)) >> 16;
  return (short)r;
}

__device__ __forceinline__ short bf16s(float f) {
  __hip_bfloat16 h = __float2bfloat16(f);
  return *reinterpret_cast<short*>(&h);
}

// ---------------- cast x fp32 -> bf16 ----------------
__global__ __launch_bounds__(256) void cast_x_kernel(const float* __restrict__ x,
                                                     short* __restrict__ xb) {
  int i = blockIdx.x * 256 + threadIdx.x;
  float4 v = ((const float4*)x)[i];
  short4 o;
  o.x = f2bf(v.x); o.y = f2bf(v.y); o.z = f2bf(v.z); o.w = f2bf(v.w);
  ((short4*)xb)[i] = o;
}

// ---------------- transpose + cast weights ----------------
__global__ __launch_bounds__(256) void transpose_cast_w(
    const float* __restrict__ w0, const float* __restrict__ w1,
    const float* __restrict__ w2, const float* __restrict__ w3,
    short* __restrict__ t0, short* __restrict__ t1,
    short* __restrict__ t2, short* __restrict__ t3) {
  const float* W = blockIdx.z == 0 ? w0 : blockIdx.z == 1 ? w1 : blockIdx.z == 2 ? w2 : w3;
  short* T       = blockIdx.z == 0 ? t0 : blockIdx.z == 1 ? t1 : blockIdx.z == 2 ? t2 : t3;
  __shared__ float tile[32][33];
  int tx = threadIdx.x, ty = threadIdx.y;
  int x0 = blockIdx.x * 32, y0 = blockIdx.y * 32;
#pragma unroll
  for (int i = 0; i < 4; ++i)
    tile[ty + i * 8][tx] = W[(y0 + ty + i * 8) * D_ + x0 + tx];
  __syncthreads();
#pragma unroll
  for (int i = 0; i < 4; ++i)
    T[(x0 + ty + i * 8) * D_ + y0 + tx] = f2bf(tile[tx][ty + i * 8]);
}

// ---------------- QKV GEMM: 128x128, BK=32 double-buffered (1 barrier/iter) ----------------
// Q pre-scaled by 1/sqrt(HD)*log2(e) so attention can exp2 raw MFMA output.
__global__ __launch_bounds__(256) void qkv_gemm(
    const short* __restrict__ xb,
    const short* __restrict__ Wqt, const short* __restrict__ Wkt, const short* __restrict__ Wvt,
    const float* __restrict__ bq, const float* __restrict__ bk, const float* __restrict__ bv,
    short* __restrict__ Qb, short* __restrict__ Kb, short* __restrict__ Vtb) {
  const int which = blockIdx.z;
  const short* Bt   = which == 0 ? Wqt : which == 1 ? Wkt : Wvt;
  const float* bias = which == 0 ? bq  : which == 1 ? bk  : bv;
  const float scl   = which == 0 ? 0.125f * 1.44269504089f : 1.0f;
  const int lane = threadIdx.x & 63, wave = threadIdx.x >> 6;
  const int l15 = lane & 15, quad = lane >> 4;
  const int wm = wave & 1, wn = wave >> 1;
  const int m0 = blockIdx.x * 128, n0 = blockIdx.y * 128;
  const int srow = lane >> 2;
  const int skp  = (lane & 3) * 8;

  __shared__ short lA[2][128 * 32];
  __shared__ short lB[2][128 * 32];

  f32x4 acc[4][4];
#pragma unroll
  for (int mi = 0; mi < 4; ++mi)
#pragma unroll
    for (int ni = 0; ni < 4; ++ni) { f32x4 z = {0.f, 0.f, 0.f, 0.f}; acc[mi][ni] = z; }

  auto stage = [&](int it, int buf) {
    int kk = it * 32;
#pragma unroll
    for (int j = 0; j < 2; ++j) {
      int c = wave * 2 + j;
      int row = c * 16 + srow;
      __builtin_amdgcn_global_load_lds(
          (gbl_short*)(xb + (m0 + row) * D_ + kk + skp),
          (lds_short*)(&lA[buf][0] + c * 512 + lane * 8), 16, 0, 0);
      __builtin_amdgcn_global_load_lds(
          (gbl_short*)(Bt + (n0 + row) * D_ + kk + skp),
          (lds_short*)(&lB[buf][0] + c * 512 + lane * 8), 16, 0, 0);
    }
  };

  stage(0, 0);
  __syncthreads();
  for (int it = 0; it < 32; ++it) {
    int cur = it & 1;
    if (it < 31) stage(it + 1, cur ^ 1);
    bf16x8 af[4], bf[4];
#pragma unroll
    for (int i = 0; i < 4; ++i) {
      af[i] = *(const bf16x8*)(&lA[cur][0] + (wm * 64 + i * 16 + l15) * 32 + quad * 8);
      bf[i] = *(const bf16x8*)(&lB[cur][0] + (wn * 64 + i * 16 + l15) * 32 + quad * 8);
    }
#pragma unroll
    for (int mi = 0; mi < 4; ++mi)
#pragma unroll
      for (int ni = 0; ni < 4; ++ni)
        acc[mi][ni] = __builtin_amdgcn_mfma_f32_16x16x32_bf16(af[mi], bf[ni], acc[mi][ni], 0, 0, 0);
    if (it < 31) __syncthreads();
  }

#pragma unroll
  for (int mi = 0; mi < 4; ++mi) {
    int m = m0 + wm * 64 + mi * 16 + quad * 4;
    int bb = m >> 11;
    int s0 = m & (S_ - 1);
#pragma unroll
    for (int ni = 0; ni < 4; ++ni) {
      int n = n0 + wn * 64 + ni * 16 + l15;
      int h = n >> 6, hd = n & 63;
      float bsv = bias[n];
      if (which < 2) {
        short* dst = which == 0 ? Qb : Kb;
#pragma unroll
        for (int r = 0; r < 4; ++r)
          dst[((bb * H_ + h) * S_ + (s0 + r)) * HD_ + hd] = f2bf((acc[mi][ni][r] + bsv) * scl);
      } else {
        short4 pk;
        pk.x = f2bf(acc[mi][ni][0] + bsv);
        pk.y = f2bf(acc[mi][ni][1] + bsv);
        pk.z = f2bf(acc[mi][ni][2] + bsv);
        pk.w = f2bf(acc[mi][ni][3] + bsv);
        *(short4*)(Vtb + ((bb * H_ + h) * HD_ + hd) * S_ + s0) = pk;
      }
    }
  }
}

// ---------------- output projection: 128x64 tile, BK=32 double-buffered ----------------
__global__ __launch_bounds__(256) void out_gemm(
    const short* __restrict__ Ob, const short* __restrict__ Wot,
    const float* __restrict__ bo, float* __restrict__ out) {
  const int lane = threadIdx.x & 63, wave = threadIdx.x >> 6;
  const int l15 = lane & 15, quad = lane >> 4;
  const int m0 = blockIdx.x * 128, n0 = blockIdx.y * 64;
  const int srow = lane >> 2;
  const int skp  = (lane & 3) * 8;

  __shared__ short lA[2][128 * 32];
  __shared__ short lB[2][64 * 32];

  f32x4 acc[2][4];
#pragma unroll
  for (int mi = 0; mi < 2; ++mi)
#pragma unroll
    for (int ni = 0; ni < 4; ++ni) { f32x4 z = {0.f, 0.f, 0.f, 0.f}; acc[mi][ni] = z; }

  auto stage = [&](int it, int buf) {
    int kk = it * 32;
#pragma unroll
    for (int j = 0; j < 2; ++j) {
      int c = wave * 2 + j;
      __builtin_amdgcn_global_load_lds(
          (gbl_short*)(Ob + (m0 + c * 16 + srow) * D_ + kk + skp),
          (lds_short*)(&lA[buf][0] + c * 512 + lane * 8), 16, 0, 0);
    }
    __builtin_amdgcn_global_load_lds(
        (gbl_short*)(Wot + (n0 + wave * 16 + srow) * D_ + kk + skp),
        (lds_short*)(&lB[buf][0] + wave * 512 + lane * 8), 16, 0, 0);
  };

  stage(0, 0);
  __syncthreads();
  for (int it = 0; it < 32; ++it) {
    int cur = it & 1;
    if (it < 31) stage(it + 1, cur ^ 1);
    bf16x8 af[2], bf[4];
#pragma unroll
    for (int i = 0; i < 2; ++i)
      af[i] = *(const bf16x8*)(&lA[cur][0] + (wave * 32 + i * 16 + l15) * 32 + quad * 8);
#pragma unroll
    for (int i = 0; i < 4; ++i)
      bf[i] = *(const bf16x8*)(&lB[cur][0] + (i * 16 + l15) * 32 + quad * 8);
#pragma unroll
    for (int mi = 0; mi < 2; ++mi)
#pragma unroll
      for (int ni = 0; ni < 4; ++ni)
        acc[mi][ni] = __builtin_amdgcn_mfma_f32_16x16x32_bf16(af[mi], bf[ni], acc[mi][ni], 0, 0, 0);
    if (it < 31) __syncthreads();
  }

#pragma unroll
  for (int mi = 0; mi < 2; ++mi) {
    int m = m0 + wave * 32 + mi * 16 + quad * 4;
#pragma unroll
    for (int ni = 0; ni < 4; ++ni) {
      int n = n0 + ni * 16 + l15;
      float bsv = bo[n];
#pragma unroll
      for (int r = 0; r < 4; ++r)
        out[(m + r) * D_ + n] = acc[mi][ni][r] + bsv;
    }
  }
}

// ---------------- Flash attention v5 ----------------
// Split-K x2 (8 waves: 4+4), 32q/wave. lP shrunk to 16 rows/wave (written+read
// per mi; wave-private, DS in-order). P stored with quad-XOR physical block
// permutation: element (row,col) at row*72 + ((col>>4)^(row>>2))*16 + (col&15)
// -> conflict-free writes. LDS 50 KB -> 3 blocks/CU.
__global__ __launch_bounds__(512, 6) void attn_kernel(
    const short* __restrict__ Qb, const short* __restrict__ Kb,
    const short* __restrict__ Vtb, short* __restrict__ Ob) {
  const int qt = blockIdx.x, h = blockIdx.y, b = blockIdx.z;
  const int base = (b * H_ + h) * S_ * HD_;
  const int tid = threadIdx.x;
  const int lane = tid & 63, wave = tid >> 6;      // 0..7
  const int grp = wave >> 2;                       // key-half
  const int wq  = wave & 3;                        // q-subtile
  const int l15 = lane & 15, quad = lane >> 4;

  __shared__ __align__(16) char smem[51200];
  short* lK  = (short*)smem;                       // [2][64*64]
  short* lV  = (short*)(smem + 16384);             // [2][64*64]
  short* lPw = (short*)(smem + 32768);             // [8][16*72]

  const int q0 = qt * 128 + wq * 32;

  bf16x8 qf[2][2];
#pragma unroll
  for (int mi = 0; mi < 2; ++mi)
#pragma unroll
    for (int ks = 0; ks < 2; ++ks)
      qf[mi][ks] = *(const bf16x8*)(Qb + base + (q0 + mi * 16 + l15) * HD_ + ks * 32 + quad * 8);

  f32x4 oacc[2][4];
  f32x4 lacc[2];
#pragma unroll
  for (int mi = 0; mi < 2; ++mi) {
    f32x4 z = {0.f, 0.f, 0.f, 0.f};
    lacc[mi] = z;
#pragma unroll
    for (int nb = 0; nb < 4; ++nb) oacc[mi][nb] = z;
  }

  bf16x8 onesf;
#pragma unroll
  for (int i = 0; i < 8; ++i) onesf[i] = (short)0x3F80;   // bf16 1.0

  // staging (per 4-wave group, XOR-swizzled 16B groups in source addr)
  const int tig  = tid & 255;
  const int slot = tig & 7;
  const int rbase = tig >> 3;
  const int sgrp = ((slot ^ (rbase & 7))) * 8;
  const short* kp = Kb + base + (grp * 1024 + rbase) * HD_ + sgrp;
  const short* vp = Vtb + base + rbase * S_ + grp * 1024 + sgrp;
  lds_short* ldk0 = (lds_short*)(lK + grp * 4096 + tig * 8);
  lds_short* ldv0 = (lds_short*)(lV + grp * 4096 + tig * 8);

  short* pw = lPw + wave * 1152;          // 16 rows x stride 72
  short* pbase = pw + quad * 4 * 72;
  const int swz = l15 & 7;

  for (int kt = 0; kt < 16; ++kt) {
#pragma unroll
    for (int j = 0; j < 2; ++j) {
      __builtin_amdgcn_global_load_lds((gbl_short*)(kp + j * 32 * HD_), ldk0 + j * 2048, 16, 0, 0);
      __builtin_amdgcn_global_load_lds((gbl_short*)(vp + j * 32 * S_),  ldv0 + j * 2048, 16, 0, 0);
    }
    kp += 64 * HD_;
    vp += 64;
    __syncthreads();

    // S = Q K^T (32q x 64keys per wave); kf reused across mi
    f32x4 sacc[2][4];
#pragma unroll
    for (int mi = 0; mi < 2; ++mi)
#pragma unroll
      for (int nb = 0; nb < 4; ++nb) { f32x4 z = {0.f, 0.f, 0.f, 0.f}; sacc[mi][nb] = z; }
#pragma unroll
    for (int nb = 0; nb < 4; ++nb)
#pragma unroll
      for (int ks = 0; ks < 2; ++ks) {
        bf16x8 kf = *(const bf16x8*)(lK + grp * 4096 + (nb * 16 + l15) * 64 + (((ks * 4 + quad) ^ swz) * 8));
        sacc[0][nb] = __builtin_amdgcn_mfma_f32_16x16x32_bf16(qf[0][ks], kf, sacc[0][nb], 0, 0, 0);
        sacc[1][nb] = __builtin_amdgcn_mfma_f32_16x16x32_bf16(qf[1][ks], kf, sacc[1][nb], 0, 0, 0);
      }

    // per-mi: P = exp2(S) -> 16-row wave-private LDS (XOR-block layout), read af
    bf16x8 af[2][2];
#pragma unroll
    for (int mi = 0; mi < 2; ++mi) {
#pragma unroll
      for (int nb = 0; nb < 4; ++nb) {
        int cofs = ((nb ^ quad) * 16) + l15;
#pragma unroll
        for (int r = 0; r < 4; ++r)
          pbase[r * 72 + cofs] = bf16s(__builtin_amdgcn_exp2f(sacc[mi][nb][r]));
      }
#pragma unroll
      for (int ks = 0; ks < 2; ++ks)
        af[mi][ks] = *(const bf16x8*)(pw + l15 * 72 +
            (((ks * 2 + (quad >> 1)) ^ (l15 >> 2)) * 16) + (quad & 1) * 8);
    }

    // O += P V ; l += P 1  (vf read once, reused across mi)
#pragma unroll
    for (int nbh = 0; nbh < 4; ++nbh)
#pragma unroll
      for (int ks = 0; ks < 2; ++ks) {
        bf16x8 vf = *(const bf16x8*)(lV + grp * 4096 + (nbh * 16 + l15) * 64 + (((ks * 4 + quad) ^ swz) * 8));
        oacc[0][nbh] = __builtin_amdgcn_mfma_f32_16x16x32_bf16(af[0][ks], vf, oacc[0][nbh], 0, 0, 0);
        oacc[1][nbh] = __builtin_amdgcn_mfma_f32_16x16x32_bf16(af[1][ks], vf, oacc[1][nbh], 0, 0, 0);
      }
#pragma unroll
    for (int mi = 0; mi < 2; ++mi) {
      lacc[mi] = __builtin_amdgcn_mfma_f32_16x16x32_bf16(af[mi][0], onesf, lacc[mi], 0, 0, 0);
      lacc[mi] = __builtin_amdgcn_mfma_f32_16x16x32_bf16(af[mi][1], onesf, lacc[mi], 0, 0, 0);
    }
    __syncthreads();
  }

  // merge key-halves through LDS (reuse lK/lV region), normalize + write
  float* exch = (float*)smem;                      // 4 waves x 32q x 64d f32 = 32 KB
  float* lex  = (float*)(smem + 32768);            // 128 floats
  if (grp == 1) {
#pragma unroll
    for (int mi = 0; mi < 2; ++mi)
#pragma unroll
      for (int nbh = 0; nbh < 4; ++nbh)
#pragma unroll
        for (int r = 0; r < 4; ++r)
          exch[wq * 2048 + (mi * 16 + quad * 4 + r) * 64 + nbh * 16 + l15] = oacc[mi][nbh][r];
    if (l15 == 0) {
#pragma unroll
      for (int mi = 0; mi < 2; ++mi)
#pragma unroll
        for (int r = 0; r < 4; ++r)
          lex[wq * 32 + mi * 16 + quad * 4 + r] = lacc[mi][r];
    }
  }
  __syncthreads();
  if (grp == 0) {
#pragma unroll
    for (int mi = 0; mi < 2; ++mi)
#pragma unroll
      for (int r = 0; r < 4; ++r) {
        int row = mi * 16 + quad * 4 + r;
        float l2 = lex[wq * 32 + row];
        float inv = 1.0f / (lacc[mi][r] + l2);
        int sg = q0 + row;
#pragma unroll
        for (int nbh = 0; nbh < 4; ++nbh) {
          float o2 = exch[wq * 2048 + row * 64 + nbh * 16 + l15];
          Ob[(b * S_ + sg) * D_ + h * HD_ + nbh * 16 + l15] =
              bf16s((oacc[mi][nbh][r] + o2) * inv);
        }
      }
  }
}

// ---------------- launcher ----------------
extern "C" void kernel_launch(void* const* d_in, const int* in_sizes, int n_in,
                              void* d_out, int out_size, void* d_ws, size_t ws_size,
                              hipStream_t stream) {
  (void)in_sizes; (void)n_in; (void)out_size; (void)ws_size;
  const float* x  = (const float*)d_in[0];
  const float* Wq = (const float*)d_in[1];
  const float* bq = (const float*)d_in[2];
  const float* Wk = (const float*)d_in[3];
  const float* bk = (const float*)d_in[4];
  const float* Wv = (const float*)d_in[5];
  const float* bv = (const float*)d_in[6];
  const float* Wo = (const float*)d_in[7];
  const float* bo = (const float*)d_in[8];
  float* out = (float*)d_out;

  char* ws = (char*)d_ws;
  short* xb  = (short*)(ws);
  short* Wqt = (short*)(ws + 8388608);
  short* Wkt = Wqt + 1048576;
  short* Wvt = Wkt + 1048576;
  short* Wot = Wvt + 1048576;
  short* Qb  = Wot + 1048576;
  short* Kb  = Qb + 4194304;
  short* Vtb = Kb + 4194304;
  short* Ob  = Vtb + 4194304;

  cast_x_kernel<<<4096, 256, 0, stream>>>(x, xb);
  transpose_cast_w<<<dim3(32, 32, 4), dim3(32, 8), 0, stream>>>(
      Wq, Wk, Wv, Wo, Wqt, Wkt, Wvt, Wot);
  qkv_gemm<<<dim3(32, 8, 3), 256, 0, stream>>>(
      xb, Wqt, Wkt, Wvt, bq, bk, bv, Qb, Kb, Vtb);
  attn_kernel<<<dim3(16, 16, 2), 512, 0, stream>>>(Qb, Kb, Vtb, Ob);
  out_gemm<<<dim3(32, 16), 256, 0, stream>>>(Ob, Wot, bo, out);
}

// Round 7
// 199.202 us; speedup vs baseline: 1.6102x; 1.6102x over previous
//
#include <hip/hip_runtime.h>
#include <hip/hip_bf16.h>

#define B_  2
#define S_  2048
#define D_  1024
#define H_  16
#define HD_ 64

typedef __attribute__((ext_vector_type(8))) short bf16x8;
typedef __attribute__((ext_vector_type(4))) float f32x4;

typedef __attribute__((address_space(1))) const short gbl_short;
typedef __attribute__((address_space(3))) short lds_short;

__device__ __forceinline__ short f2bf(float f) {
  union { float f; unsigned u; } v; v.f = f;
  unsigned r = (v.u + 0x7FFFu + ((v.u >> 16) & 1u)) >> 16;
  return (short)r;
}

__device__ __forceinline__ short bf16s(float f) {
  __hip_bfloat16 h = __float2bfloat16(f);
  return *reinterpret_cast<short*>(&h);
}

// ---------------- cast x fp32 -> bf16 ----------------
__global__ __launch_bounds__(256) void cast_x_kernel(const float* __restrict__ x,
                                                     short* __restrict__ xb) {
  int i = blockIdx.x * 256 + threadIdx.x;
  float4 v = ((const float4*)x)[i];
  short4 o;
  o.x = f2bf(v.x); o.y = f2bf(v.y); o.z = f2bf(v.z); o.w = f2bf(v.w);
  ((short4*)xb)[i] = o;
}

// ---------------- transpose + cast weights ----------------
__global__ __launch_bounds__(256) void transpose_cast_w(
    const float* __restrict__ w0, const float* __restrict__ w1,
    const float* __restrict__ w2, const float* __restrict__ w3,
    short* __restrict__ t0, short* __restrict__ t1,
    short* __restrict__ t2, short* __restrict__ t3) {
  const float* W = blockIdx.z == 0 ? w0 : blockIdx.z == 1 ? w1 : blockIdx.z == 2 ? w2 : w3;
  short* T       = blockIdx.z == 0 ? t0 : blockIdx.z == 1 ? t1 : blockIdx.z == 2 ? t2 : t3;
  __shared__ float tile[32][33];
  int tx = threadIdx.x, ty = threadIdx.y;
  int x0 = blockIdx.x * 32, y0 = blockIdx.y * 32;
#pragma unroll
  for (int i = 0; i < 4; ++i)
    tile[ty + i * 8][tx] = W[(y0 + ty + i * 8) * D_ + x0 + tx];
  __syncthreads();
#pragma unroll
  for (int i = 0; i < 4; ++i)
    T[(x0 + ty + i * 8) * D_ + y0 + tx] = f2bf(tile[tx][ty + i * 8]);
}

// ---------------- QKV GEMM: 128x128, BK=32 double-buffered (1 barrier/iter) ----------------
// Q pre-scaled by 1/sqrt(HD)*log2(e) so attention can exp2 raw MFMA output.
__global__ __launch_bounds__(256) void qkv_gemm(
    const short* __restrict__ xb,
    const short* __restrict__ Wqt, const short* __restrict__ Wkt, const short* __restrict__ Wvt,
    const float* __restrict__ bq, const float* __restrict__ bk, const float* __restrict__ bv,
    short* __restrict__ Qb, short* __restrict__ Kb, short* __restrict__ Vtb) {
  const int which = blockIdx.z;
  const short* Bt   = which == 0 ? Wqt : which == 1 ? Wkt : Wvt;
  const float* bias = which == 0 ? bq  : which == 1 ? bk  : bv;
  const float scl   = which == 0 ? 0.125f * 1.44269504089f : 1.0f;
  const int lane = threadIdx.x & 63, wave = threadIdx.x >> 6;
  const int l15 = lane & 15, quad = lane >> 4;
  const int wm = wave & 1, wn = wave >> 1;
  const int m0 = blockIdx.x * 128, n0 = blockIdx.y * 128;
  const int srow = lane >> 2;
  const int skp  = (lane & 3) * 8;

  __shared__ short lA[2][128 * 32];
  __shared__ short lB[2][128 * 32];

  f32x4 acc[4][4];
#pragma unroll
  for (int mi = 0; mi < 4; ++mi)
#pragma unroll
    for (int ni = 0; ni < 4; ++ni) { f32x4 z = {0.f, 0.f, 0.f, 0.f}; acc[mi][ni] = z; }

  auto stage = [&](int it, int buf) {
    int kk = it * 32;
#pragma unroll
    for (int j = 0; j < 2; ++j) {
      int c = wave * 2 + j;
      int row = c * 16 + srow;
      __builtin_amdgcn_global_load_lds(
          (gbl_short*)(xb + (m0 + row) * D_ + kk + skp),
          (lds_short*)(&lA[buf][0] + c * 512 + lane * 8), 16, 0, 0);
      __builtin_amdgcn_global_load_lds(
          (gbl_short*)(Bt + (n0 + row) * D_ + kk + skp),
          (lds_short*)(&lB[buf][0] + c * 512 + lane * 8), 16, 0, 0);
    }
  };

  stage(0, 0);
  __syncthreads();
  for (int it = 0; it < 32; ++it) {
    int cur = it & 1;
    if (it < 31) stage(it + 1, cur ^ 1);
    bf16x8 af[4], bf[4];
#pragma unroll
    for (int i = 0; i < 4; ++i) {
      af[i] = *(const bf16x8*)(&lA[cur][0] + (wm * 64 + i * 16 + l15) * 32 + quad * 8);
      bf[i] = *(const bf16x8*)(&lB[cur][0] + (wn * 64 + i * 16 + l15) * 32 + quad * 8);
    }
#pragma unroll
    for (int mi = 0; mi < 4; ++mi)
#pragma unroll
      for (int ni = 0; ni < 4; ++ni)
        acc[mi][ni] = __builtin_amdgcn_mfma_f32_16x16x32_bf16(af[mi], bf[ni], acc[mi][ni], 0, 0, 0);
    if (it < 31) __syncthreads();
  }

#pragma unroll
  for (int mi = 0; mi < 4; ++mi) {
    int m = m0 + wm * 64 + mi * 16 + quad * 4;
    int bb = m >> 11;
    int s0 = m & (S_ - 1);
#pragma unroll
    for (int ni = 0; ni < 4; ++ni) {
      int n = n0 + wn * 64 + ni * 16 + l15;
      int h = n >> 6, hd = n & 63;
      float bsv = bias[n];
      if (which < 2) {
        short* dst = which == 0 ? Qb : Kb;
#pragma unroll
        for (int r = 0; r < 4; ++r)
          dst[((bb * H_ + h) * S_ + (s0 + r)) * HD_ + hd] = f2bf((acc[mi][ni][r] + bsv) * scl);
      } else {
        short4 pk;
        pk.x = f2bf(acc[mi][ni][0] + bsv);
        pk.y = f2bf(acc[mi][ni][1] + bsv);
        pk.z = f2bf(acc[mi][ni][2] + bsv);
        pk.w = f2bf(acc[mi][ni][3] + bsv);
        *(short4*)(Vtb + ((bb * H_ + h) * HD_ + hd) * S_ + s0) = pk;
      }
    }
  }
}

// ---------------- output projection: 128x64 tile, BK=32 double-buffered ----------------
__global__ __launch_bounds__(256) void out_gemm(
    const short* __restrict__ Ob, const short* __restrict__ Wot,
    const float* __restrict__ bo, float* __restrict__ out) {
  const int lane = threadIdx.x & 63, wave = threadIdx.x >> 6;
  const int l15 = lane & 15, quad = lane >> 4;
  const int m0 = blockIdx.x * 128, n0 = blockIdx.y * 64;
  const int srow = lane >> 2;
  const int skp  = (lane & 3) * 8;

  __shared__ short lA[2][128 * 32];
  __shared__ short lB[2][64 * 32];

  f32x4 acc[2][4];
#pragma unroll
  for (int mi = 0; mi < 2; ++mi)
#pragma unroll
    for (int ni = 0; ni < 4; ++ni) { f32x4 z = {0.f, 0.f, 0.f, 0.f}; acc[mi][ni] = z; }

  auto stage = [&](int it, int buf) {
    int kk = it * 32;
#pragma unroll
    for (int j = 0; j < 2; ++j) {
      int c = wave * 2 + j;
      __builtin_amdgcn_global_load_lds(
          (gbl_short*)(Ob + (m0 + c * 16 + srow) * D_ + kk + skp),
          (lds_short*)(&lA[buf][0] + c * 512 + lane * 8), 16, 0, 0);
    }
    __builtin_amdgcn_global_load_lds(
        (gbl_short*)(Wot + (n0 + wave * 16 + srow) * D_ + kk + skp),
        (lds_short*)(&lB[buf][0] + wave * 512 + lane * 8), 16, 0, 0);
  };

  stage(0, 0);
  __syncthreads();
  for (int it = 0; it < 32; ++it) {
    int cur = it & 1;
    if (it < 31) stage(it + 1, cur ^ 1);
    bf16x8 af[2], bf[4];
#pragma unroll
    for (int i = 0; i < 2; ++i)
      af[i] = *(const bf16x8*)(&lA[cur][0] + (wave * 32 + i * 16 + l15) * 32 + quad * 8);
#pragma unroll
    for (int i = 0; i < 4; ++i)
      bf[i] = *(const bf16x8*)(&lB[cur][0] + (i * 16 + l15) * 32 + quad * 8);
#pragma unroll
    for (int mi = 0; mi < 2; ++mi)
#pragma unroll
      for (int ni = 0; ni < 4; ++ni)
        acc[mi][ni] = __builtin_amdgcn_mfma_f32_16x16x32_bf16(af[mi], bf[ni], acc[mi][ni], 0, 0, 0);
    if (it < 31) __syncthreads();
  }

#pragma unroll
  for (int mi = 0; mi < 2; ++mi) {
    int m = m0 + wave * 32 + mi * 16 + quad * 4;
#pragma unroll
    for (int ni = 0; ni < 4; ++ni) {
      int n = n0 + ni * 16 + l15;
      float bsv = bo[n];
#pragma unroll
      for (int r = 0; r < 4; ++r)
        out[(m + r) * D_ + n] = acc[mi][ni][r] + bsv;
    }
  }
}

// ---------------- Flash attention v5b ----------------
// Split-K x2 (8 waves: 4+4), 32q/wave, 16-row/wave P with XOR-block layout.
// LDS 50 KB -> 3 blocks/CU (LDS-bound). launch_bounds min-waves=4 (VGPR cap
// 128): round-6's min-waves=6 capped VGPRs at ~85 and spilled every
// accumulator to scratch (362 MB write traffic, 3x regression).
__global__ __launch_bounds__(512, 4) void attn_kernel(
    const short* __restrict__ Qb, const short* __restrict__ Kb,
    const short* __restrict__ Vtb, short* __restrict__ Ob) {
  const int qt = blockIdx.x, h = blockIdx.y, b = blockIdx.z;
  const int base = (b * H_ + h) * S_ * HD_;
  const int tid = threadIdx.x;
  const int lane = tid & 63, wave = tid >> 6;      // 0..7
  const int grp = wave >> 2;                       // key-half
  const int wq  = wave & 3;                        // q-subtile
  const int l15 = lane & 15, quad = lane >> 4;

  __shared__ __align__(16) char smem[51200];
  short* lK  = (short*)smem;                       // [2][64*64]
  short* lV  = (short*)(smem + 16384);             // [2][64*64]
  short* lPw = (short*)(smem + 32768);             // [8][16*72]

  const int q0 = qt * 128 + wq * 32;

  bf16x8 qf[2][2];
#pragma unroll
  for (int mi = 0; mi < 2; ++mi)
#pragma unroll
    for (int ks = 0; ks < 2; ++ks)
      qf[mi][ks] = *(const bf16x8*)(Qb + base + (q0 + mi * 16 + l15) * HD_ + ks * 32 + quad * 8);

  f32x4 oacc[2][4];
  f32x4 lacc[2];
#pragma unroll
  for (int mi = 0; mi < 2; ++mi) {
    f32x4 z = {0.f, 0.f, 0.f, 0.f};
    lacc[mi] = z;
#pragma unroll
    for (int nb = 0; nb < 4; ++nb) oacc[mi][nb] = z;
  }

  bf16x8 onesf;
#pragma unroll
  for (int i = 0; i < 8; ++i) onesf[i] = (short)0x3F80;   // bf16 1.0

  // staging (per 4-wave group, XOR-swizzled 16B groups in source addr)
  const int tig  = tid & 255;
  const int slot = tig & 7;
  const int rbase = tig >> 3;
  const int sgrp = ((slot ^ (rbase & 7))) * 8;
  const short* kp = Kb + base + (grp * 1024 + rbase) * HD_ + sgrp;
  const short* vp = Vtb + base + rbase * S_ + grp * 1024 + sgrp;
  lds_short* ldk0 = (lds_short*)(lK + grp * 4096 + tig * 8);
  lds_short* ldv0 = (lds_short*)(lV + grp * 4096 + tig * 8);

  short* pw = lPw + wave * 1152;          // 16 rows x stride 72
  short* pbase = pw + quad * 4 * 72;
  const int swz = l15 & 7;

  for (int kt = 0; kt < 16; ++kt) {
#pragma unroll
    for (int j = 0; j < 2; ++j) {
      __builtin_amdgcn_global_load_lds((gbl_short*)(kp + j * 32 * HD_), ldk0 + j * 2048, 16, 0, 0);
      __builtin_amdgcn_global_load_lds((gbl_short*)(vp + j * 32 * S_),  ldv0 + j * 2048, 16, 0, 0);
    }
    kp += 64 * HD_;
    vp += 64;
    __syncthreads();

    // S = Q K^T (32q x 64keys per wave); kf reused across mi
    f32x4 sacc[2][4];
#pragma unroll
    for (int mi = 0; mi < 2; ++mi)
#pragma unroll
      for (int nb = 0; nb < 4; ++nb) { f32x4 z = {0.f, 0.f, 0.f, 0.f}; sacc[mi][nb] = z; }
#pragma unroll
    for (int nb = 0; nb < 4; ++nb)
#pragma unroll
      for (int ks = 0; ks < 2; ++ks) {
        bf16x8 kf = *(const bf16x8*)(lK + grp * 4096 + (nb * 16 + l15) * 64 + (((ks * 4 + quad) ^ swz) * 8));
        sacc[0][nb] = __builtin_amdgcn_mfma_f32_16x16x32_bf16(qf[0][ks], kf, sacc[0][nb], 0, 0, 0);
        sacc[1][nb] = __builtin_amdgcn_mfma_f32_16x16x32_bf16(qf[1][ks], kf, sacc[1][nb], 0, 0, 0);
      }

    // per-mi: P = exp2(S) -> 16-row wave-private LDS (XOR-block layout), read af
    bf16x8 af[2][2];
#pragma unroll
    for (int mi = 0; mi < 2; ++mi) {
#pragma unroll
      for (int nb = 0; nb < 4; ++nb) {
        int cofs = ((nb ^ quad) * 16) + l15;
#pragma unroll
        for (int r = 0; r < 4; ++r)
          pbase[r * 72 + cofs] = bf16s(__builtin_amdgcn_exp2f(sacc[mi][nb][r]));
      }
#pragma unroll
      for (int ks = 0; ks < 2; ++ks)
        af[mi][ks] = *(const bf16x8*)(pw + l15 * 72 +
            (((ks * 2 + (quad >> 1)) ^ (l15 >> 2)) * 16) + (quad & 1) * 8);
    }

    // O += P V ; l += P 1  (vf read once, reused across mi)
#pragma unroll
    for (int nbh = 0; nbh < 4; ++nbh)
#pragma unroll
      for (int ks = 0; ks < 2; ++ks) {
        bf16x8 vf = *(const bf16x8*)(lV + grp * 4096 + (nbh * 16 + l15) * 64 + (((ks * 4 + quad) ^ swz) * 8));
        oacc[0][nbh] = __builtin_amdgcn_mfma_f32_16x16x32_bf16(af[0][ks], vf, oacc[0][nbh], 0, 0, 0);
        oacc[1][nbh] = __builtin_amdgcn_mfma_f32_16x16x32_bf16(af[1][ks], vf, oacc[1][nbh], 0, 0, 0);
      }
#pragma unroll
    for (int mi = 0; mi < 2; ++mi) {
      lacc[mi] = __builtin_amdgcn_mfma_f32_16x16x32_bf16(af[mi][0], onesf, lacc[mi], 0, 0, 0);
      lacc[mi] = __builtin_amdgcn_mfma_f32_16x16x32_bf16(af[mi][1], onesf, lacc[mi], 0, 0, 0);
    }
    __syncthreads();
  }

  // merge key-halves through LDS (reuse lK/lV region), normalize + write
  float* exch = (float*)smem;                      // 4 waves x 32q x 64d f32 = 32 KB
  float* lex  = (float*)(smem + 32768);            // 128 floats
  if (grp == 1) {
#pragma unroll
    for (int mi = 0; mi < 2; ++mi)
#pragma unroll
      for (int nbh = 0; nbh < 4; ++nbh)
#pragma unroll
        for (int r = 0; r < 4; ++r)
          exch[wq * 2048 + (mi * 16 + quad * 4 + r) * 64 + nbh * 16 + l15] = oacc[mi][nbh][r];
    if (l15 == 0) {
#pragma unroll
      for (int mi = 0; mi < 2; ++mi)
#pragma unroll
        for (int r = 0; r < 4; ++r)
          lex[wq * 32 + mi * 16 + quad * 4 + r] = lacc[mi][r];
    }
  }
  __syncthreads();
  if (grp == 0) {
#pragma unroll
    for (int mi = 0; mi < 2; ++mi)
#pragma unroll
      for (int r = 0; r < 4; ++r) {
        int row = mi * 16 + quad * 4 + r;
        float l2 = lex[wq * 32 + row];
        float inv = 1.0f / (lacc[mi][r] + l2);
        int sg = q0 + row;
#pragma unroll
        for (int nbh = 0; nbh < 4; ++nbh) {
          float o2 = exch[wq * 2048 + row * 64 + nbh * 16 + l15];
          Ob[(b * S_ + sg) * D_ + h * HD_ + nbh * 16 + l15] =
              bf16s((oacc[mi][nbh][r] + o2) * inv);
        }
      }
  }
}

// ---------------- launcher ----------------
extern "C" void kernel_launch(void* const* d_in, const int* in_sizes, int n_in,
                              void* d_out, int out_size, void* d_ws, size_t ws_size,
                              hipStream_t stream) {
  (void)in_sizes; (void)n_in; (void)out_size; (void)ws_size;
  const float* x  = (const float*)d_in[0];
  const float* Wq = (const float*)d_in[1];
  const float* bq = (const float*)d_in[2];
  const float* Wk = (const float*)d_in[3];
  const float* bk = (const float*)d_in[4];
  const float* Wv = (const float*)d_in[5];
  const float* bv = (const float*)d_in[6];
  const float* Wo = (const float*)d_in[7];
  const float* bo = (const float*)d_in[8];
  float* out = (float*)d_out;

  char* ws = (char*)d_ws;
  short* xb  = (short*)(ws);
  short* Wqt = (short*)(ws + 8388608);
  short* Wkt = Wqt + 1048576;
  short* Wvt = Wkt + 1048576;
  short* Wot = Wvt + 1048576;
  short* Qb  = Wot + 1048576;
  short* Kb  = Qb + 4194304;
  short* Vtb = Kb + 4194304;
  short* Ob  = Vtb + 4194304;

  cast_x_kernel<<<4096, 256, 0, stream>>>(x, xb);
  transpose_cast_w<<<dim3(32, 32, 4), dim3(32, 8), 0, stream>>>(
      Wq, Wk, Wv, Wo, Wqt, Wkt, Wvt, Wot);
  qkv_gemm<<<dim3(32, 8, 3), 256, 0, stream>>>(
      xb, Wqt, Wkt, Wvt, bq, bk, bv, Qb, Kb, Vtb);
  attn_kernel<<<dim3(16, 16, 2), 512, 0, stream>>>(Qb, Kb, Vtb, Ob);
  out_gemm<<<dim3(32, 16), 256, 0, stream>>>(Ob, Wot, bo, out);
}